// Round 6
// baseline (104.617 us; speedup 1.0000x reference)
//
#include <hip/hip_runtime.h>
#include <type_traits>

// ---------------------------------------------------------------------------
// Complex Daubechies wavelet pyramid, 6 levels, circular boundary, 6 taps.
// d_out = [B, C, 2, H, W] fp32. One tiled dispatch per level (fused column
// pass -> row pass). LL band of levels 0..4 goes ONLY to ws; level 5 writes
// LL to d_out. Filters: LO palindromic, HI antipalindromic -> 6 taps fold to 3.
// R6 structure: per-HALF input staging (s4 holds TB+5 rows, not 2TB+5) ->
// 4 blocks/CU complex levels; half-1 loads issued under half-0 stage-3 (T14);
// stage-2 reads ds_read_b64 column pairs; y stride YW=2TB+4 (==4 mod 32) so
// stage-3 b128 window reads hit the 32-bank floor.
// ---------------------------------------------------------------------------

#define SQ2 0.7071067811865476

constexpr float kLOR0 = (float)(-0.0662912607 * SQ2);
constexpr float kLOR1 = (float)( 0.1104854346 * SQ2);
constexpr float kLOR2 = (float)( 0.6629126074 * SQ2);
constexpr float kLOI0 = (float)(-0.0855816496 * SQ2);
constexpr float kLOI1 = (float)(-0.0855816496 * SQ2);
constexpr float kLOI2 = (float)( 0.1711632992 * SQ2);
constexpr float kHIR0 = (float)(-0.0662912607 * SQ2);
constexpr float kHIR1 = (float)(-0.1104854346 * SQ2);
constexpr float kHIR2 = (float)( 0.6629126074 * SQ2);
constexpr float kHII0 = (float)( 0.0855816496 * SQ2);
constexpr float kHII1 = (float)(-0.0855816496 * SQ2);
constexpr float kHII2 = (float)(-0.1711632992 * SQ2);

typedef float f4v __attribute__((ext_vector_type(4)));
typedef float f2v __attribute__((ext_vector_type(2)));

// 6-tap complex filter pair via (anti)symmetry; inputs statically indexed.
template <bool IM>
__device__ __forceinline__ void cconv6(const float* xr, const float* xi,
                                       float& lr, float& li, float& hr,
                                       float& hi) {
  const float s0 = xr[0] + xr[5], s1 = xr[1] + xr[4], s2 = xr[2] + xr[3];
  const float d0 = xr[0] - xr[5], d1 = xr[1] - xr[4], d2 = xr[2] - xr[3];
  lr = kLOR0 * s0 + kLOR1 * s1 + kLOR2 * s2;
  li = kLOI0 * s0 + kLOI1 * s1 + kLOI2 * s2;
  hr = kHIR0 * d0 + kHIR1 * d1 + kHIR2 * d2;
  hi = kHII0 * d0 + kHII1 * d1 + kHII2 * d2;
  if (IM) {
    const float t0 = xi[0] + xi[5], t1 = xi[1] + xi[4], t2 = xi[2] + xi[3];
    const float e0 = xi[0] - xi[5], e1 = xi[1] - xi[4], e2 = xi[2] - xi[3];
    lr -= kLOI0 * t0 + kLOI1 * t1 + kLOI2 * t2;
    li += kLOR0 * t0 + kLOR1 * t1 + kLOR2 * t2;
    hr -= kHII0 * e0 + kHII1 * e1 + kHII2 * e2;
    hi += kHIR0 * e0 + kHIR1 * e1 + kHIR2 * e2;
  }
}

__device__ __forceinline__ void gload16(const f4v* src, f4v* ldsDst) {
  __builtin_amdgcn_global_load_lds(
      (__attribute__((address_space(1))) const void*)src,
      (__attribute__((address_space(3))) void*)ldsDst, 16, 0, 0);
}

// ---------------------------- tiled level kernel ---------------------------
template <int TB, bool HAS_IMAG, bool LL_TO_WS>
__global__ __launch_bounds__(256) void dwt_kernel(
    const float* __restrict__ inR, const float* __restrict__ inI,
    float* __restrict__ out, float* __restrict__ llR, float* __restrict__ llI,
    int h, int w, int tilesPerRow, int tilesPerPlane, int cpx8, int HW,
    int W0) {
  constexpr int RH = TB + 5;                 // input rows per half
  constexpr int F4PR = TB / 2 + 2;           // float4 per input row
  constexpr int SW = 4 * F4PR;               // LDS row stride (floats)
  constexpr int NF4H = RH * F4PR;
  constexpr int NF4HP = ((NF4H + 63) / 64) * 64;
  constexpr int C2 = 2 * TB + 4;             // stage-2 outputs per row
  constexpr int YW = C2;                     // 68/36: ==4 mod 32, mult of 4
  constexpr int HB = TB / 2;                 // output rows per half
  constexpr int NJQ4 = TB / 4;               // stage-3 col groups (4 wide)
  constexpr int NU = TB + 2;                 // stage-2 units per row

  __shared__ f4v s4R[NF4HP];
  __shared__ f4v s4I[HAS_IMAG ? NF4HP : 1];
  __shared__ __align__(16) float yLR[HB * YW], yLI[HB * YW];
  __shared__ __align__(16) float yHR[HB * YW], yHI[HB * YW];

  const int tid = threadIdx.x;
  int bid = (int)blockIdx.x;
  bid = (bid & 7) * cpx8 + (bid >> 3);  // XCD-contiguous chunks
  const int plane = bid / tilesPerPlane;
  const int trem = bid - plane * tilesPerPlane;
  const int ti = trem / tilesPerRow;
  const int tj = trem - ti * tilesPerRow;

  const int hm = h - 1;
  const int w4 = w >> 2, w4m = w4 - 1;
  const int col4start = HB * tj - 1;

  const float* pinR = inR + (size_t)plane * h * w;
  const float* pinI = HAS_IMAG ? (inI + (size_t)plane * h * w) : nullptr;

  const float* sRf = (const float*)s4R;
  const float* sIf = (const float*)s4I;
  const int i0 = TB * ti, j0g = TB * tj;
  const int h2 = h >> 1, w2 = w >> 1;
  float* outR = out + (size_t)plane * 2 * HW;
  float* outI = outR + HW;

  // ---- stage 1: issue async global->LDS for half p ----
  auto stage1 = [&](int p) {
    const int rowstart = 2 * TB * ti + TB * p - 3;
    const int lane = tid & 63;
    const int wid = tid >> 6;
    for (int c0 = wid * 64; c0 < NF4HP; c0 += 256) {
      const int idx = c0 + lane;
      const int r = idx / F4PR;
      const int q = idx - r * F4PR;
      const int gr = (rowstart + r) & hm;
      const int gq = (col4start + q) & w4m;
      const size_t goff = (size_t)gr * w4 + gq;
      gload16((const f4v*)pinR + goff, &s4R[c0]);
      if (HAS_IMAG) gload16((const f4v*)pinI + goff, &s4I[c0]);
    }
  };

  // ---- stage 2: column pass on resident half; 2 cols/thread (b64) ----
  auto stage2 = [&]() {
    for (int idx = tid; idx < HB * NU; idx += 256) {
      const int il = idx / NU;
      const int u = idx - il * NU;
      const int yo = il * YW;
      const float* bR = sRf + 2 * il * SW;
      const float* bI = sIf + 2 * il * SW;
      if (u == 0) {
        // edges: y[0] <- col 1, y[C2-1] <- col C2
        float ar[6], ai[6];
        float lr, li, hr, hi;
#pragma unroll
        for (int k = 0; k < 6; ++k) {
          ar[k] = bR[k * SW + 1];
          if (HAS_IMAG) ai[k] = bI[k * SW + 1];
        }
        cconv6<HAS_IMAG>(ar, ai, lr, li, hr, hi);
        yLR[yo] = lr;
        yLI[yo] = li;
        yHR[yo] = hr;
        yHI[yo] = hi;
#pragma unroll
        for (int k = 0; k < 6; ++k) {
          ar[k] = bR[k * SW + C2];
          if (HAS_IMAG) ai[k] = bI[k * SW + C2];
        }
        cconv6<HAS_IMAG>(ar, ai, lr, li, hr, hi);
        yLR[yo + C2 - 1] = lr;
        yLI[yo + C2 - 1] = li;
        yHR[yo + C2 - 1] = hr;
        yHI[yo + C2 - 1] = hi;
      } else {
        const int cc = 2 * u;  // even -> 8B-aligned b64 reads
        float ar[6], ai[6], br[6], bi[6];
#pragma unroll
        for (int k = 0; k < 6; ++k) {
          const f2v v = *(const f2v*)(bR + k * SW + cc);
          ar[k] = v.x;
          br[k] = v.y;
          if (HAS_IMAG) {
            const f2v z = *(const f2v*)(bI + k * SW + cc);
            ai[k] = z.x;
            bi[k] = z.y;
          }
        }
        float lr0, li0, hr0, hi0, lr1, li1, hr1, hi1;
        cconv6<HAS_IMAG>(ar, ai, lr0, li0, hr0, hi0);
        cconv6<HAS_IMAG>(br, bi, lr1, li1, hr1, hi1);
        yLR[yo + cc - 1] = lr0;
        yLR[yo + cc] = lr1;
        yLI[yo + cc - 1] = li0;
        yLI[yo + cc] = li1;
        yHR[yo + cc - 1] = hr0;
        yHR[yo + cc] = hr1;
        yHI[yo + cc - 1] = hi0;
        yHI[yo + cc] = hi1;
      }
    }
  };

  // ---- stage 3: row pass for half p; 4 cols/thread, b128 windows ----
  auto stage3 = [&](int p) {
    const int jq = tid & (NJQ4 - 1);
    const int il = tid / NJQ4;
    if (il < HB) {
      const int base = il * YW + 8 * jq;  // y[8jq .. 8jq+11]
      float xLR[12], xLI[12], xHR[12], xHI[12];
      *(f4v*)&xLR[0] = *(const f4v*)&yLR[base];
      *(f4v*)&xLR[4] = *(const f4v*)&yLR[base + 4];
      *(f4v*)&xLR[8] = *(const f4v*)&yLR[base + 8];
      *(f4v*)&xLI[0] = *(const f4v*)&yLI[base];
      *(f4v*)&xLI[4] = *(const f4v*)&yLI[base + 4];
      *(f4v*)&xLI[8] = *(const f4v*)&yLI[base + 8];
      *(f4v*)&xHR[0] = *(const f4v*)&yHR[base];
      *(f4v*)&xHR[4] = *(const f4v*)&yHR[base + 4];
      *(f4v*)&xHR[8] = *(const f4v*)&yHR[base + 8];
      *(f4v*)&xHI[0] = *(const f4v*)&yHI[base];
      *(f4v*)&xHI[4] = *(const f4v*)&yHI[base + 4];
      *(f4v*)&xHI[8] = *(const f4v*)&yHI[base + 8];
      float o[8][4];
#pragma unroll
      for (int u = 0; u < 4; ++u) {
        cconv6<true>(&xLR[2 * u], &xLI[2 * u], o[0][u], o[1][u], o[2][u],
                     o[3][u]);
        cconv6<true>(&xHR[2 * u], &xHI[2 * u], o[4][u], o[5][u], o[6][u],
                     o[7][u]);
      }
      const int gi = i0 + p * HB + il;
      const int gj = j0g + 4 * jq;
      const int rlo = gi, rhi = h2 + gi, clo = gj, chi = w2 + gj;
      auto st = [&](float* pdst, int v) {
        f4v t;
        t.x = o[v][0];
        t.y = o[v][1];
        t.z = o[v][2];
        t.w = o[v][3];
        __builtin_nontemporal_store(t, (f4v*)pdst);
      };
      st(outR + (size_t)rlo * W0 + chi, 2);  // LH
      st(outI + (size_t)rlo * W0 + chi, 3);
      st(outR + (size_t)rhi * W0 + clo, 4);  // HL
      st(outI + (size_t)rhi * W0 + clo, 5);
      st(outR + (size_t)rhi * W0 + chi, 6);  // HH
      st(outI + (size_t)rhi * W0 + chi, 7);
      if (LL_TO_WS) {
        const size_t off = (size_t)plane * h2 * w2 + (size_t)gi * w2 + gj;
        f4v a, b;
        a.x = o[0][0];
        a.y = o[0][1];
        a.z = o[0][2];
        a.w = o[0][3];
        b.x = o[1][0];
        b.y = o[1][1];
        b.z = o[1][2];
        b.w = o[1][3];
        *(f4v*)(llR + off) = a;  // cached: next level reads these
        *(f4v*)(llI + off) = b;
      } else {
        st(outR + (size_t)rlo * W0 + clo, 0);  // LL (final level)
        st(outI + (size_t)rlo * W0 + clo, 1);
      }
    }
  };

  // Schedule: half-1 loads issued before half-0 stage-3 so HBM latency hides
  // under compute; the following barrier drains vmcnt.
  stage1(0);
  __syncthreads();
  stage2();
  __syncthreads();
  stage1(1);
  stage3(0);
  __syncthreads();
  stage2();
  __syncthreads();
  stage3(1);
}

extern "C" void kernel_launch(void* const* d_in, const int* in_sizes, int n_in,
                              void* d_out, int out_size, void* d_ws,
                              size_t ws_size, hipStream_t stream) {
  const float* images = (const float*)d_in[0];
  float* out = (float*)d_out;
  constexpr int B = 8, C = 3, H = 1024, W = 1024;
  constexpr int NP = B * C;

  float* wsf = (float*)d_ws;
  const size_t S0 = (size_t)NP * 512 * 512;
  const size_t S1 = (size_t)NP * 256 * 256;
  float* buf0R = wsf;
  float* buf0I = wsf + S0;
  float* buf1R = wsf + 2 * S0;
  float* buf1I = wsf + 2 * S0 + S1;

  auto launch = [&](auto tb_tag, bool hasImag, bool llToWs, const float* iR,
                    const float* iI, float* lR, float* lI, int hsz) {
    constexpr int TB = decltype(tb_tag)::value;
    const int tpr = (hsz / 2) / TB;
    const int tpp = tpr * tpr;
    const int grid = NP * tpp;
    if (!hasImag) {
      dwt_kernel<TB, false, true><<<grid, 256, 0, stream>>>(
          iR, nullptr, out, lR, lI, hsz, hsz, tpr, tpp, grid / 8, H * W, W);
    } else if (llToWs) {
      dwt_kernel<TB, true, true><<<grid, 256, 0, stream>>>(
          iR, iI, out, lR, lI, hsz, hsz, tpr, tpp, grid / 8, H * W, W);
    } else {
      dwt_kernel<TB, true, false><<<grid, 256, 0, stream>>>(
          iR, iI, out, nullptr, nullptr, hsz, hsz, tpr, tpp, grid / 8, H * W,
          W);
    }
  };

  launch(std::integral_constant<int, 32>{}, false, true, images, nullptr,
         buf0R, buf0I, 1024);                                   // L0
  launch(std::integral_constant<int, 32>{}, true, true, buf0R, buf0I, buf1R,
         buf1I, 512);                                           // L1
  launch(std::integral_constant<int, 32>{}, true, true, buf1R, buf1I, buf0R,
         buf0I, 256);                                           // L2
  launch(std::integral_constant<int, 32>{}, true, true, buf0R, buf0I, buf1R,
         buf1I, 128);                                           // L3
  launch(std::integral_constant<int, 16>{}, true, true, buf1R, buf1I, buf0R,
         buf0I, 64);                                            // L4
  launch(std::integral_constant<int, 16>{}, true, false, buf0R, buf0I,
         nullptr, nullptr, 32);                                 // L5
}

// Round 8
// 88.964 us; speedup vs baseline: 1.1759x; 1.1759x over previous
//
#include <hip/hip_runtime.h>
#include <type_traits>

// ---------------------------------------------------------------------------
// Complex Daubechies wavelet pyramid, 6 levels, circular boundary, 6 taps.
// d_out = [B, C, 2, H, W] fp32. One tiled dispatch per level. LL of levels
// 0..4 -> ws only (overwritten in d_out by next level); level 5 -> d_out.
// R8 structure: ONE barrier per tile. After staging, each WAVE owns 4 band
// rows per pass: stage-2 (column pass) lane=col into wave-private y slots,
// wave-level s_waitcnt lgkmcnt(0) (no __syncthreads), stage-3 (row pass)
// lane=(subrow r, colpair q) reads its slot's window as 2x ds_read_b128
// (slot stride C2=2TB+4 == 4 mod 32 -> conflict-free), stores f2v bands.
// Filters: LO palindromic, HI antipalindromic -> 6 taps fold to 3.
// ---------------------------------------------------------------------------

#define SQ2 0.7071067811865476

constexpr float kLOR0 = (float)(-0.0662912607 * SQ2);
constexpr float kLOR1 = (float)( 0.1104854346 * SQ2);
constexpr float kLOR2 = (float)( 0.6629126074 * SQ2);
constexpr float kLOI0 = (float)(-0.0855816496 * SQ2);
constexpr float kLOI1 = (float)(-0.0855816496 * SQ2);
constexpr float kLOI2 = (float)( 0.1711632992 * SQ2);
constexpr float kHIR0 = (float)(-0.0662912607 * SQ2);
constexpr float kHIR1 = (float)(-0.1104854346 * SQ2);
constexpr float kHIR2 = (float)( 0.6629126074 * SQ2);
constexpr float kHII0 = (float)( 0.0855816496 * SQ2);
constexpr float kHII1 = (float)(-0.0855816496 * SQ2);
constexpr float kHII2 = (float)(-0.1711632992 * SQ2);

typedef float f4v __attribute__((ext_vector_type(4)));
typedef float f2v __attribute__((ext_vector_type(2)));

// 6-tap complex filter pair via (anti)symmetry; inputs statically indexed.
template <bool IM>
__device__ __forceinline__ void cconv6(const float* xr, const float* xi,
                                       float& lr, float& li, float& hr,
                                       float& hi) {
  const float s0 = xr[0] + xr[5], s1 = xr[1] + xr[4], s2 = xr[2] + xr[3];
  const float d0 = xr[0] - xr[5], d1 = xr[1] - xr[4], d2 = xr[2] - xr[3];
  lr = kLOR0 * s0 + kLOR1 * s1 + kLOR2 * s2;
  li = kLOI0 * s0 + kLOI1 * s1 + kLOI2 * s2;
  hr = kHIR0 * d0 + kHIR1 * d1 + kHIR2 * d2;
  hi = kHII0 * d0 + kHII1 * d1 + kHII2 * d2;
  if (IM) {
    const float t0 = xi[0] + xi[5], t1 = xi[1] + xi[4], t2 = xi[2] + xi[3];
    const float e0 = xi[0] - xi[5], e1 = xi[1] - xi[4], e2 = xi[2] - xi[3];
    lr -= kLOI0 * t0 + kLOI1 * t1 + kLOI2 * t2;
    li += kLOR0 * t0 + kLOR1 * t1 + kLOR2 * t2;
    hr -= kHII0 * e0 + kHII1 * e1 + kHII2 * e2;
    hi += kHIR0 * e0 + kHIR1 * e1 + kHIR2 * e2;
  }
}

__device__ __forceinline__ void gload16(const f4v* src, f4v* ldsDst) {
  __builtin_amdgcn_global_load_lds(
      (__attribute__((address_space(1))) const void*)src,
      (__attribute__((address_space(3))) void*)ldsDst, 16, 0, 0);
}

// ---------------------------- tiled level kernel ---------------------------
template <int TB, bool HAS_IMAG, bool LL_TO_WS>
__global__ __launch_bounds__(256) void dwt_kernel(
    const float* __restrict__ inR, const float* __restrict__ inI,
    float* __restrict__ out, float* __restrict__ llR, float* __restrict__ llI,
    int h, int w, int tilesPerRow, int tilesPerPlane, int cpx8, int HW,
    int W0) {
  constexpr int RROWS = 2 * TB + 4;   // input rows staged
  constexpr int F4PR = TB / 2 + 2;    // float4 per input row
  constexpr int SW = 4 * F4PR;        // LDS row stride (floats)
  constexpr int NF4 = RROWS * F4PR;
  constexpr int NF4P = ((NF4 + 255) / 256) * 256;
  constexpr int C2 = 2 * TB + 4;      // y cols; ==4 mod 32, mult of 4
  constexpr int NPASS = TB / 16;      // 16 band rows per pass (4 waves x 4)
  constexpr int QACT = (TB / 2 < 16) ? TB / 2 : 16;  // active colpair lanes

  __shared__ f4v s4R[NF4P];
  __shared__ f4v s4I[HAS_IMAG ? NF4P : 1];
  // 16 slots (4 waves x 4 rows), wave-private.
  __shared__ __align__(16) float yLR[16 * C2], yLI[16 * C2];
  __shared__ __align__(16) float yHR[16 * C2], yHI[16 * C2];

  const int tid = threadIdx.x;
  int bid = (int)blockIdx.x;
  bid = (bid & 7) * cpx8 + (bid >> 3);  // XCD-contiguous chunks
  const int plane = bid / tilesPerPlane;
  const int trem = bid - plane * tilesPerPlane;
  const int ti = trem / tilesPerRow;
  const int tj = trem - ti * tilesPerRow;

  const int hm = h - 1;
  const int w4 = w >> 2, w4m = w4 - 1;
  const int rowstart = 2 * TB * ti - 3;
  const int col4start = (TB / 2) * tj - 1;

  const float* pinR = inR + (size_t)plane * h * w;
  const float* pinI = HAS_IMAG ? (inI + (size_t)plane * h * w) : nullptr;

  // ---- stage 1: global -> LDS, width-16 async, linear LDS layout ----
  {
    const int lane = tid & 63;
    const int wid = tid >> 6;
    for (int c0 = wid * 64; c0 < NF4P; c0 += 256) {
      const int idx = c0 + lane;
      const int rr = idx / F4PR;
      const int qq = idx - rr * F4PR;
      const int gr = (rowstart + rr) & hm;
      const int gq = (col4start + qq) & w4m;
      const size_t goff = (size_t)gr * w4 + gq;
      gload16((const f4v*)pinR + goff, &s4R[c0]);
      if (HAS_IMAG) gload16((const f4v*)pinI + goff, &s4I[c0]);
    }
  }
  __syncthreads();  // the ONLY block barrier per tile

  const float* sRf = (const float*)s4R;
  const float* sIf = (const float*)s4I;
  const int i0 = TB * ti, j0g = TB * tj;
  const int h2 = h >> 1, w2 = w >> 1;
  float* outR = out + (size_t)plane * 2 * HW;
  float* outI = outR + HW;

  const int wv = tid >> 6;
  const int lane = tid & 63;
  const int r = lane >> 4, q = lane & 15;

  for (int p = 0; p < NPASS; ++p) {
    const int ibase = p * 16 + wv * 4;  // this wave's 4 band rows

    // ---- stage 2: column pass, lane = col, 4 rows, wave-private slots ----
    {
      auto s2col = [&](int c) {
        const float* cR = sRf + (2 * ibase) * SW + c + 1;
        const float* cI = sIf + (2 * ibase) * SW + c + 1;
        float xr[12], xi[12];
#pragma unroll
        for (int m = 0; m < 12; ++m) {
          xr[m] = cR[m * SW];
          if (HAS_IMAG) xi[m] = cI[m * SW];
        }
#pragma unroll
        for (int k = 0; k < 4; ++k) {
          float lr, li, hr, hi;
          cconv6<HAS_IMAG>(&xr[2 * k], &xi[2 * k], lr, li, hr, hi);
          const int yi = (wv * 4 + k) * C2 + c;
          yLR[yi] = lr;
          yLI[yi] = li;
          yHR[yi] = hr;
          yHI[yi] = hi;
        }
      };
      if (C2 >= 64) {
        s2col(lane);
        // leftover cols 64..C2-1: one (col,row) item per lane, single conv
        if (lane < 4 * (C2 - 64)) {
          const int ce = 64 + (lane >> 2);
          const int ke = lane & 3;
          const float* cR = sRf + (2 * (ibase + ke)) * SW + ce + 1;
          const float* cI = sIf + (2 * (ibase + ke)) * SW + ce + 1;
          float xr[6], xi[6];
#pragma unroll
          for (int m = 0; m < 6; ++m) {
            xr[m] = cR[m * SW];
            if (HAS_IMAG) xi[m] = cI[m * SW];
          }
          float lr, li, hr, hi;
          cconv6<HAS_IMAG>(xr, xi, lr, li, hr, hi);
          const int yi = (wv * 4 + ke) * C2 + ce;
          yLR[yi] = lr;
          yLI[yi] = li;
          yHR[yi] = hr;
          yHI[yi] = hi;
        }
      } else {
        if (lane < C2) s2col(lane);
      }
    }
    // Wave-level fence: all this wave's ds_writes complete before its lanes
    // read each other's y values. No block barrier needed (slots private).
    asm volatile("s_waitcnt lgkmcnt(0)" ::: "memory");
    __builtin_amdgcn_sched_barrier(0);

    // ---- stage 3: row pass; lane=(subrow r, colpair q), b128 windows ----
    if (q < QACT) {
      const int slot = wv * 4 + r;
      const int base = slot * C2 + 4 * q;
      float xLR[8], xLI[8], xHR[8], xHI[8];
      *(f4v*)&xLR[0] = *(const f4v*)&yLR[base];
      *(f4v*)&xLR[4] = *(const f4v*)&yLR[base + 4];
      *(f4v*)&xLI[0] = *(const f4v*)&yLI[base];
      *(f4v*)&xLI[4] = *(const f4v*)&yLI[base + 4];
      *(f4v*)&xHR[0] = *(const f4v*)&yHR[base];
      *(f4v*)&xHR[4] = *(const f4v*)&yHR[base + 4];
      *(f4v*)&xHI[0] = *(const f4v*)&yHI[base];
      *(f4v*)&xHI[4] = *(const f4v*)&yHI[base + 4];
      float o[8][2];
#pragma unroll
      for (int u = 0; u < 2; ++u) {  // col 2q+u window = x[2u .. 2u+5]
        cconv6<true>(&xLR[2 * u], &xLI[2 * u], o[0][u], o[1][u], o[2][u],
                     o[3][u]);
        cconv6<true>(&xHR[2 * u], &xHI[2 * u], o[4][u], o[5][u], o[6][u],
                     o[7][u]);
      }
      const int gi = i0 + ibase + r;
      const int gj = j0g + 2 * q;
      const int rlo = gi, rhi = h2 + gi, clo = gj, chi = w2 + gj;
      auto st = [&](float* pdst, int v) {
        f2v t;
        t.x = o[v][0];
        t.y = o[v][1];
        __builtin_nontemporal_store(t, (f2v*)pdst);
      };
      st(outR + (size_t)rlo * W0 + chi, 2);  // LH
      st(outI + (size_t)rlo * W0 + chi, 3);
      st(outR + (size_t)rhi * W0 + clo, 4);  // HL
      st(outI + (size_t)rhi * W0 + clo, 5);
      st(outR + (size_t)rhi * W0 + chi, 6);  // HH
      st(outI + (size_t)rhi * W0 + chi, 7);
      if (LL_TO_WS) {
        const size_t off = (size_t)plane * h2 * w2 + (size_t)gi * w2 + gj;
        f2v a, b;
        a.x = o[0][0];
        a.y = o[0][1];
        b.x = o[1][0];
        b.y = o[1][1];
        *(f2v*)(llR + off) = a;  // cached: next level reads these
        *(f2v*)(llI + off) = b;
      } else {
        st(outR + (size_t)rlo * W0 + clo, 0);  // LL (final level)
        st(outI + (size_t)rlo * W0 + clo, 1);
      }
    }
    // No barrier between passes: pass p+1 overwrites only THIS wave's slots,
    // and per-wave LDS ops are in-order (may-alias => compiler keeps order).
  }
}

extern "C" void kernel_launch(void* const* d_in, const int* in_sizes, int n_in,
                              void* d_out, int out_size, void* d_ws,
                              size_t ws_size, hipStream_t stream) {
  const float* images = (const float*)d_in[0];
  float* out = (float*)d_out;
  constexpr int B = 8, C = 3, H = 1024, W = 1024;
  constexpr int NP = B * C;

  float* wsf = (float*)d_ws;
  const size_t S0 = (size_t)NP * 512 * 512;
  const size_t S1 = (size_t)NP * 256 * 256;
  float* buf0R = wsf;
  float* buf0I = wsf + S0;
  float* buf1R = wsf + 2 * S0;
  float* buf1I = wsf + 2 * S0 + S1;

  auto launch = [&](auto tb_tag, bool hasImag, bool llToWs, const float* iR,
                    const float* iI, float* lR, float* lI, int hsz) {
    constexpr int TB = decltype(tb_tag)::value;
    const int tpr = (hsz / 2) / TB;
    const int tpp = tpr * tpr;
    const int grid = NP * tpp;
    if (!hasImag) {
      dwt_kernel<TB, false, true><<<grid, 256, 0, stream>>>(
          iR, nullptr, out, lR, lI, hsz, hsz, tpr, tpp, grid / 8, H * W, W);
    } else if (llToWs) {
      dwt_kernel<TB, true, true><<<grid, 256, 0, stream>>>(
          iR, iI, out, lR, lI, hsz, hsz, tpr, tpp, grid / 8, H * W, W);
    } else {
      dwt_kernel<TB, true, false><<<grid, 256, 0, stream>>>(
          iR, iI, out, nullptr, nullptr, hsz, hsz, tpr, tpp, grid / 8, H * W,
          W);
    }
  };

  launch(std::integral_constant<int, 32>{}, false, true, images, nullptr,
         buf0R, buf0I, 1024);                                   // L0
  launch(std::integral_constant<int, 32>{}, true, true, buf0R, buf0I, buf1R,
         buf1I, 512);                                           // L1
  launch(std::integral_constant<int, 32>{}, true, true, buf1R, buf1I, buf0R,
         buf0I, 256);                                           // L2
  launch(std::integral_constant<int, 32>{}, true, true, buf0R, buf0I, buf1R,
         buf1I, 128);                                           // L3
  launch(std::integral_constant<int, 16>{}, true, true, buf1R, buf1I, buf0R,
         buf0I, 64);                                            // L4
  launch(std::integral_constant<int, 16>{}, true, false, buf0R, buf0I,
         nullptr, nullptr, 32);                                 // L5
}